// Round 9
// baseline (247.832 us; speedup 1.0000x reference)
//
#include <hip/hip_runtime.h>
#include <stdint.h>

typedef unsigned long long u64;
typedef unsigned int u32;

#define NB 8
#define NN 2048
#define NC 80
#define ROW 84
#define OUT_K 200
#define IOU_T 0.5f
#define SCORE_T 0.01f
#define NG 10   // class-groups of 8 per batch

// ---- compare-exchange, descending network, direction from global index ----
__device__ __forceinline__ void ce_desc(u64* a, int i, int j, int k) {
    u64 a0 = a[i], a1 = a[i + j];
    bool up = ((i & k) == 0);
    if (up ? (a0 < a1) : (a0 > a1)) { a[i] = a1; a[i + j] = a0; }
}

// wave-local rounds on a 512-elem segment (4 CE/lane/round), j<=256
__device__ __forceinline__ void wave_rounds512(u64* a, int base, int k, int jhi, int lane) {
    for (int j = jhi; j > 0; j >>= 1) {
        #pragma unroll
        for (int p = 0; p < 4; p++) {
            int r = lane + p * 64;
            int low = r & (j - 1);
            int high = (r & ~(j - 1)) << 1;
            ce_desc(a, base + (high | low), j, k);
        }
        __builtin_amdgcn_wave_barrier();
    }
}

// wave-local rounds on a 256-elem segment; k=0x40000000 -> all-descending merge
__device__ __forceinline__ void wave_rounds256(u64* a, int base, int k, int jhi, int lane) {
    for (int j = jhi; j > 0; j >>= 1) {
        #pragma unroll
        for (int p = 0; p < 2; p++) {
            int r = lane + p * 64;
            int low = r & (j - 1);
            int high = (r & ~(j - 1)) << 1;
            ce_desc(a, base + (high | low), j, k);
        }
        __builtin_amdgcn_wave_barrier();
    }
}

// max-combine two desc-sorted 256-runs (base, base+off) -> top-256 sorted desc
__device__ __forceinline__ void pair_merge256(u64* a, int base, int off, int lane) {
    #pragma unroll
    for (int p0 = 0; p0 < 4; p0++) {
        int p = lane + p0 * 64;
        u64 xv = a[base + p];
        u64 yv = a[base + off + 255 - p];
        a[base + p] = xv > yv ? xv : yv;
    }
    __builtin_amdgcn_wave_barrier();
    wave_rounds256(a, base, 0x40000000, 128, lane);
}

// full hybrid bitonic sort of 2048 (desc) — identical network to rounds 4-8
__device__ __forceinline__ void sort2048(u64* key, int tid, int lane, int wv) {
    const int base = wv * 512;
    for (int k = 2; k <= 512; k <<= 1)
        wave_rounds512(key, base, k, k >> 1, lane);
    __syncthreads();
    #pragma unroll
    for (int p = 0; p < 4; p++) {                       // k=1024, j=512
        int r = tid + p * 256;
        int low = r & 511, high = (r & ~511) << 1;
        ce_desc(key, high | low, 512, 1024);
    }
    __syncthreads();
    wave_rounds512(key, base, 1024, 256, lane);
    __syncthreads();
    #pragma unroll
    for (int p = 0; p < 4; p++) {                       // k=2048, j=1024
        int r = tid + p * 256;
        int low = r & 1023, high = (r & ~1023) << 1;
        ce_desc(key, high | low, 1024, 2048);
    }
    __syncthreads();
    #pragma unroll
    for (int p = 0; p < 4; p++) {                       // k=2048, j=512
        int r = tid + p * 256;
        int low = r & 511, high = (r & ~511) << 1;
        ce_desc(key, high | low, 512, 2048);
    }
    __syncthreads();
    wave_rounds512(key, base, 2048, 256, lane);
    __syncthreads();
}

// exact reference-order IoU > 0.5 test (byte-identical to passing rounds 3-8)
__device__ __forceinline__ bool iou_gt_half(float4 a, float aa, float4 b, float ab) {
    float ltx = fmaxf(a.x, b.x);
    float lty = fmaxf(a.y, b.y);
    float rbx = fminf(a.z, b.z);
    float rby = fminf(a.w, b.w);
    float wd = fmaxf(__fsub_rn(rbx, ltx), 0.0f);
    float hd = fmaxf(__fsub_rn(rby, lty), 0.0f);
    float inter = __fmul_rn(wd, hd);
    float uni = __fsub_rn(__fadd_rn(aa, ab), inter);
    float m = fmaxf(uni, 1e-8f);
    float d2 = __fmul_rn(2.0f, inter);     // exact scaling
    bool sup = d2 > m;                      // == (inter/m > 0.5) exactly
    if (sup && (__fsub_rn(d2, m) <= __fmul_rn(m, 1.2e-7f)))
        sup = __fdiv_rn(inter, m) > IOU_T;  // fdiv boundary guard, ~never taken
    return sup;
}

__device__ __forceinline__ float bcast(float v, int sl) {
    return __int_as_float(__builtin_amdgcn_readlane(__float_as_int(v), sl));
}

// ---- single fused kernel: R6-verbatim NMS + two-level in-kernel top-k ----
__global__ __launch_bounds__(256) void nms_fused(
        const float* __restrict__ x, u64* __restrict__ cand_key,
        u64* __restrict__ ws2, int* __restrict__ cnt_g, int* __restrict__ cnt_b,
        float* __restrict__ out) {
    const int bc = blockIdx.x;
    const int b = bc / NC;
    const int c = bc % NC;
    const int tid = threadIdx.x;
    const int lane = tid & 63;
    const int wv = tid >> 6;

    // carved LDS (~22 KB, same budget as round-6's 22.5 KB kernel):
    //  [0,16384)      key[2048]           (aliased: gbuf[2048] group merge)
    //  [16384,19584)  kept_box[200]       (aliased by mbuf)
    //  [19584,20384)  kept_area[200]      (aliased by mbuf)
    //  [20384,21984)  kept_key[200]       (aliased by mbuf tail)
    //  mbuf[2560] u64 = [0,20480) for the batch merge
    __shared__ __align__(16) unsigned char smem[21984];
    u64* key = (u64*)smem;
    float4* kept_box = (float4*)(smem + 16384);
    float* kept_area = (float*)(smem + 19584);
    u64* kept_key = (u64*)(smem + 20384);
    u64* gbuf = (u64*)smem;
    u64* mbuf = (u64*)smem;
    __shared__ u64 s_sup[4];
    __shared__ int s_kept, s_done, s_role;

    const float* xb = x + (size_t)b * NN * ROW;

    // build keys (score desc, index asc) — R6 exact
    #pragma unroll
    for (int w = 0; w < 8; w++) {
        int n = w * 256 + tid;
        float sc = xb[n * ROW + 4 + c];
        key[n] = ((u64)__float_as_uint(sc) << 32) | (u64)(0xFFFFFFFFu - (u32)n);
    }
    if (tid == 0) { s_kept = 0; s_done = 0; }
    __syncthreads();
    sort2048(key, tid, lane, wv);

    // ---- R6-verbatim chunked greedy: 4-wave kept-test + wave-0 scan ----
    int keptc = 0;
    for (int ch = 0; ch < 32; ch++) {
        int n = ch * 64 + lane;
        u64 mykey = key[n];
        float sc = __uint_as_float((u32)(mykey >> 32));
        bool valid = sc > SCORE_T;
        u64 vball = __ballot(valid);       // identical on all 4 waves
        if (vball == 0ULL) break;

        u32 orig = 0xFFFFFFFFu - (u32)(mykey & 0xFFFFFFFFu);
        float4 bx = *(const float4*)(xb + (size_t)orig * ROW);
        float ar = __fmul_rn(__fsub_rn(bx.z, bx.x), __fsub_rn(bx.w, bx.y));

        // wave wv tests vs kept[t], t ≡ wv (mod 4); broadcast LDS reads, x4
        bool supA = false;
        int t = wv;
        for (; t + 12 < keptc; t += 16) {
            float4 kb0 = kept_box[t],     kb1 = kept_box[t + 4];
            float4 kb2 = kept_box[t + 8], kb3 = kept_box[t + 12];
            float ka0 = kept_area[t],     ka1 = kept_area[t + 4];
            float ka2 = kept_area[t + 8], ka3 = kept_area[t + 12];
            bool s0 = iou_gt_half(bx, ar, kb0, ka0);
            bool s1 = iou_gt_half(bx, ar, kb1, ka1);
            bool s2 = iou_gt_half(bx, ar, kb2, ka2);
            bool s3 = iou_gt_half(bx, ar, kb3, ka3);
            supA = supA | ((s0 | s1) | (s2 | s3));
        }
        for (; t < keptc; t += 4)
            supA = supA | iou_gt_half(bx, ar, kept_box[t], kept_area[t]);
        u64 supm = __ballot(supA);
        if (lane == 0) s_sup[wv] = supm;
        __syncthreads();                   // B1

        if (wv == 0) {
            u64 alive = vball & ~s_sup[0] & ~s_sup[1] & ~s_sup[2] & ~s_sup[3];
            int kept = keptc;
            while (alive) {
                int bsel = (int)__builtin_ctzll(alive);
                if (lane == bsel) {
                    kept_key[kept] = mykey;
                    kept_box[kept] = bx;
                    kept_area[kept] = ar;
                }
                kept++;
                if (kept >= OUT_K) { s_done = 1; break; }
                alive &= alive - 1;
                if (!alive) break;
                float4 pb = make_float4(bcast(bx.x, bsel), bcast(bx.y, bsel),
                                        bcast(bx.z, bsel), bcast(bx.w, bsel));
                float pa = bcast(ar, bsel);
                alive &= ~__ballot(iou_gt_half(bx, ar, pb, pa));
            }
            if (lane == 0) s_kept = kept;
        }
        __syncthreads();                   // B2
        keptc = s_kept;
        if (s_done) break;
        if (__popcll(vball) < 64) break;   // sorted: nothing valid beyond
    }
    __syncthreads();
    const int kept_final = s_kept;

    // emit 200 keys; low32 packs ((0x3FFF - (c*200+slot)) << 11) | orig_idx
    // -> cross-class order (score desc, flat asc) matches reference top_k
    const int base_o = bc * OUT_K;
    if (tid < OUT_K) {
        u64 ok = 0ULL;
        if (tid < kept_final) {
            u64 kk = kept_key[tid];
            u32 flat = (u32)(c * OUT_K + tid);
            u32 orig = 0xFFFFFFFFu - (u32)(kk & 0xFFFFFFFFu);   // < 2048
            ok = (kk & 0xFFFFFFFF00000000ULL) |
                 ((u64)(0x3FFFu - flat) << 11) | (u64)orig;
        }
        cand_key[base_o + tid] = ok;
    }

    // ---- fused finish: 8th finisher per class-group merges 8 runs -> ws2;
    //      10th group-finisher per batch merges 10 runs of 256, decodes ----
    __threadfence();                      // release cand_key
    if (tid == 0) {
        int old = atomicAdd(&cnt_g[b * NG + (c >> 3)], 1);
        s_role = (old == 7) ? 1 : 0;
    }
    __syncthreads();
    if (s_role == 1) {
        __threadfence();                  // acquire group's cand_key
        const int g = c >> 3;
        const u64* src = cand_key + (size_t)(b * NC + g * 8) * OUT_K;
        for (int i = tid; i < 2048; i += 256) {
            int run = i >> 8, pos = i & 255;
            gbuf[i] = (pos < OUT_K) ? src[run * OUT_K + pos] : 0ULL;
        }
        __syncthreads();
        pair_merge256(gbuf, wv * 512, 256, lane);
        __syncthreads();
        if (wv < 2) pair_merge256(gbuf, wv * 1024, 512, lane);
        __syncthreads();
        if (wv == 0) pair_merge256(gbuf, 0, 1024, lane);
        __syncthreads();
        ws2[(size_t)b * 2560 + g * 256 + tid] = gbuf[tid];
        __threadfence();                  // release ws2
        if (tid == 0) {
            int old2 = atomicAdd(&cnt_b[b], 1);
            s_role = (old2 == NG - 1) ? 2 : 0;
        }
        __syncthreads();
        if (s_role == 2) {
            __threadfence();              // acquire batch's ws2
            for (int i = tid; i < 2560; i += 256)
                mbuf[i] = ws2[(size_t)b * 2560 + i];
            __syncthreads();
            // tournament over 10 runs of 256 within 2560 words:
            // A: (0,256)(512,768)(1024,1280)(1536,1792)(2048,2304)
            pair_merge256(mbuf, wv * 512, 256, lane);
            if (wv == 0) pair_merge256(mbuf, 2048, 256, lane);
            __syncthreads();
            // B: (0,512) and (1024,1536)
            if (wv == 0) pair_merge256(mbuf, 0, 512, lane);
            else if (wv == 1) pair_merge256(mbuf, 1024, 512, lane);
            __syncthreads();
            // C: (0,1024)
            if (wv == 0) pair_merge256(mbuf, 0, 1024, lane);
            __syncthreads();
            // D: (0,2048)
            if (wv == 0) pair_merge256(mbuf, 0, 2048, lane);
            __syncthreads();
            // decode top-200
            if (tid < OUT_K) {
                u64 kk = mbuf[tid];
                float* o = out + ((size_t)b * OUT_K + tid) * 6;
                if (kk == 0ULL) {
                    o[0] = 0.f; o[1] = 0.f; o[2] = 0.f;
                    o[3] = 0.f; o[4] = 0.f; o[5] = 0.f;
                } else {
                    u32 lo = (u32)(kk & 0xFFFFFFFFu);
                    u32 flat = 0x3FFFu - ((lo >> 11) & 0x3FFFu);
                    int cls = flat / OUT_K;
                    u32 n2 = lo & 0x7FFu;
                    float scf = __uint_as_float((u32)(kk >> 32));
                    float4 bb = *(const float4*)(xb + (size_t)n2 * ROW);
                    o[0] = (float)cls;
                    o[1] = scf;
                    o[2] = fminf(fmaxf(bb.x, 0.0f), 1.0f);
                    o[3] = fminf(fmaxf(bb.y, 0.0f), 1.0f);
                    o[4] = fminf(fmaxf(bb.z, 0.0f), 1.0f);
                    o[5] = fminf(fmaxf(bb.w, 0.0f), 1.0f);
                }
            }
        }
    }
}

extern "C" void kernel_launch(void* const* d_in, const int* in_sizes, int n_in,
                              void* d_out, int out_size, void* d_ws, size_t ws_size,
                              hipStream_t stream) {
    const float* x = (const float*)d_in[0];
    float* out = (float*)d_out;
    // ws: cand_key 8*80*200*8 = 1,024,000 B
    //     ws2      8*2560*8   =   163,840 B
    //     counters (80+8)*4   =       352 B
    u64* cand_key = (u64*)d_ws;
    u64* ws2 = (u64*)((char*)d_ws + 1024000);
    int* cnt_g = (int*)((char*)d_ws + 1024000 + 163840);
    int* cnt_b = cnt_g + NB * NG;
    hipMemsetAsync((void*)cnt_g, 0, (NB * NG + NB) * sizeof(int), stream);
    nms_fused<<<NB * NC, 256, 0, stream>>>(x, cand_key, ws2, cnt_g, cnt_b, out);
}

// Round 10
// 189.632 us; speedup vs baseline: 1.3069x; 1.3069x over previous
//
#include <hip/hip_runtime.h>
#include <stdint.h>

typedef unsigned long long u64;
typedef unsigned int u32;
typedef unsigned short u16;

#define NB 8
#define NN 2048
#define NC 80
#define ROW 84
#define OUT_K 200
#define IOU_T 0.5f
#define SCORE_T 0.01f

// ---- compare-exchange, descending network, direction from global index ----
__device__ __forceinline__ void ce_desc(u64* a, int i, int j, int k) {
    u64 a0 = a[i], a1 = a[i + j];
    bool up = ((i & k) == 0);
    if (up ? (a0 < a1) : (a0 > a1)) { a[i] = a1; a[i + j] = a0; }
}

// wave-local rounds on a 512-elem segment (4 CE/lane/round), j<=256
__device__ __forceinline__ void wave_rounds512(u64* a, int base, int k, int jhi, int lane) {
    for (int j = jhi; j > 0; j >>= 1) {
        #pragma unroll
        for (int p = 0; p < 4; p++) {
            int r = lane + p * 64;
            int low = r & (j - 1);
            int high = (r & ~(j - 1)) << 1;
            ce_desc(a, base + (high | low), j, k);
        }
        __builtin_amdgcn_wave_barrier();
    }
}

// wave-local rounds on a 256-elem segment; k=0x40000000 -> all-descending merge
__device__ __forceinline__ void wave_rounds256(u64* a, int base, int k, int jhi, int lane) {
    for (int j = jhi; j > 0; j >>= 1) {
        #pragma unroll
        for (int p = 0; p < 2; p++) {
            int r = lane + p * 64;
            int low = r & (j - 1);
            int high = (r & ~(j - 1)) << 1;
            ce_desc(a, base + (high | low), j, k);
        }
        __builtin_amdgcn_wave_barrier();
    }
}

// max-combine two desc-sorted 256-runs (base, base+off) -> top-256 sorted desc
__device__ __forceinline__ void pair_merge256(u64* a, int base, int off, int lane) {
    #pragma unroll
    for (int p0 = 0; p0 < 4; p0++) {
        int p = lane + p0 * 64;
        u64 xv = a[base + p];
        u64 yv = a[base + off + 255 - p];
        a[base + p] = xv > yv ? xv : yv;
    }
    __builtin_amdgcn_wave_barrier();
    wave_rounds256(a, base, 0x40000000, 128, lane);
}

// full hybrid bitonic sort of 2048 (desc) — identical network to rounds 4-9
__device__ __forceinline__ void sort2048(u64* key, int tid, int lane, int wv) {
    const int base = wv * 512;
    for (int k = 2; k <= 512; k <<= 1)
        wave_rounds512(key, base, k, k >> 1, lane);
    __syncthreads();
    #pragma unroll
    for (int p = 0; p < 4; p++) {                       // k=1024, j=512
        int r = tid + p * 256;
        int low = r & 511, high = (r & ~511) << 1;
        ce_desc(key, high | low, 512, 1024);
    }
    __syncthreads();
    wave_rounds512(key, base, 1024, 256, lane);
    __syncthreads();
    #pragma unroll
    for (int p = 0; p < 4; p++) {                       // k=2048, j=1024
        int r = tid + p * 256;
        int low = r & 1023, high = (r & ~1023) << 1;
        ce_desc(key, high | low, 1024, 2048);
    }
    __syncthreads();
    #pragma unroll
    for (int p = 0; p < 4; p++) {                       // k=2048, j=512
        int r = tid + p * 256;
        int low = r & 511, high = (r & ~511) << 1;
        ce_desc(key, high | low, 512, 2048);
    }
    __syncthreads();
    wave_rounds512(key, base, 2048, 256, lane);
    __syncthreads();
}

// exact reference-order IoU > 0.5 test (byte-identical to passing rounds 3-9)
__device__ __forceinline__ bool iou_gt_half(float4 a, float aa, float4 b, float ab) {
    float ltx = fmaxf(a.x, b.x);
    float lty = fmaxf(a.y, b.y);
    float rbx = fminf(a.z, b.z);
    float rby = fminf(a.w, b.w);
    float wd = fmaxf(__fsub_rn(rbx, ltx), 0.0f);
    float hd = fmaxf(__fsub_rn(rby, lty), 0.0f);
    float inter = __fmul_rn(wd, hd);
    float uni = __fsub_rn(__fadd_rn(aa, ab), inter);
    float m = fmaxf(uni, 1e-8f);
    float d2 = __fmul_rn(2.0f, inter);     // exact scaling
    bool sup = d2 > m;                      // == (inter/m > 0.5) exactly
    if (sup && (__fsub_rn(d2, m) <= __fmul_rn(m, 1.2e-7f)))
        sup = __fdiv_rn(inter, m) > IOU_T;  // fdiv boundary guard, ~never taken
    return sup;
}

__device__ __forceinline__ float bcast(float v, int sl) {
    return __int_as_float(__builtin_amdgcn_readlane(__float_as_int(v), sl));
}

// ---- Kernel A: R6 greedy, with LDS-staged boxes for sorted pos < 1024 ----
__global__ __launch_bounds__(256) void nms_kernel(
        const float* __restrict__ x, u64* __restrict__ cand_key) {
    const int bc = blockIdx.x;
    const int b = bc / NC;
    const int c = bc % NC;
    const int tid = threadIdx.x;
    const int lane = tid & 63;
    const int wv = tid >> 6;

    // LDS: key[2048] 16K | sbox[1024] 16K | kept_box 3.2K | kept_area 0.8K
    //      | kept_slot 0.4K  (~37 KB -> >=4 blocks/CU by LDS)
    __shared__ __align__(16) unsigned char smem[16384 + 16384 + 3200 + 800 + 400];
    u64* key = (u64*)smem;                          // [2048]
    float4* sbox = (float4*)(smem + 16384);         // [1024] sorted boxes
    float4* kept_box = (float4*)(smem + 32768);     // [200]
    float* kept_area = (float*)(smem + 35968);      // [200]
    u16* kept_slot = (u16*)(smem + 36768);          // [200]
    __shared__ u64 s_sup[4];
    __shared__ int s_kept, s_done;

    const float* xb = x + (size_t)b * NN * ROW;

    // build keys (score desc, index asc) — R6 exact
    #pragma unroll
    for (int w = 0; w < 8; w++) {
        int n = w * 256 + tid;
        float sc = xb[n * ROW + 4 + c];
        key[n] = ((u64)__float_as_uint(sc) << 32) | (u64)(0xFFFFFFFFu - (u32)n);
    }
    if (tid == 0) { s_kept = 0; s_done = 0; }
    __syncthreads();
    sort2048(key, tid, lane, wv);

    // stage boxes for the first 1024 sorted positions (4 gathers/thread, MLP)
    #pragma unroll
    for (int w = 0; w < 4; w++) {
        int n = w * 256 + tid;
        u32 orig = 0xFFFFFFFFu - (u32)(key[n] & 0xFFFFFFFFu);
        sbox[n] = *(const float4*)(xb + (size_t)orig * ROW);
    }
    __syncthreads();

    // ---- R6-verbatim chunked greedy: 4-wave kept-test + wave-0 scan ----
    int keptc = 0;
    for (int ch = 0; ch < 32; ch++) {
        int n = ch * 64 + lane;
        u64 mykey = key[n];
        float sc = __uint_as_float((u32)(mykey >> 32));
        bool valid = sc > SCORE_T;
        u64 vball = __ballot(valid);       // identical on all 4 waves
        if (vball == 0ULL) break;

        float4 bx;
        if (ch < 16) {
            bx = sbox[n];                  // staged: no global gather on path
        } else {
            u32 orig = 0xFFFFFFFFu - (u32)(mykey & 0xFFFFFFFFu);
            bx = *(const float4*)(xb + (size_t)orig * ROW);
        }
        float ar = __fmul_rn(__fsub_rn(bx.z, bx.x), __fsub_rn(bx.w, bx.y));

        // wave wv tests vs kept[t], t ≡ wv (mod 4); broadcast LDS reads, x4
        bool supA = false;
        int t = wv;
        for (; t + 12 < keptc; t += 16) {
            float4 kb0 = kept_box[t],     kb1 = kept_box[t + 4];
            float4 kb2 = kept_box[t + 8], kb3 = kept_box[t + 12];
            float ka0 = kept_area[t],     ka1 = kept_area[t + 4];
            float ka2 = kept_area[t + 8], ka3 = kept_area[t + 12];
            bool s0 = iou_gt_half(bx, ar, kb0, ka0);
            bool s1 = iou_gt_half(bx, ar, kb1, ka1);
            bool s2 = iou_gt_half(bx, ar, kb2, ka2);
            bool s3 = iou_gt_half(bx, ar, kb3, ka3);
            supA = supA | ((s0 | s1) | (s2 | s3));
        }
        for (; t < keptc; t += 4)
            supA = supA | iou_gt_half(bx, ar, kept_box[t], kept_area[t]);
        u64 supm = __ballot(supA);
        if (lane == 0) s_sup[wv] = supm;
        __syncthreads();                   // B1

        if (wv == 0) {
            u64 alive = vball & ~s_sup[0] & ~s_sup[1] & ~s_sup[2] & ~s_sup[3];
            int kept = keptc;
            while (alive) {
                int bsel = (int)__builtin_ctzll(alive);
                if (lane == bsel) {
                    kept_slot[kept] = (u16)n;
                    kept_box[kept] = bx;
                    kept_area[kept] = ar;
                }
                kept++;
                if (kept >= OUT_K) { s_done = 1; break; }
                alive &= alive - 1;
                if (!alive) break;
                float4 pb = make_float4(bcast(bx.x, bsel), bcast(bx.y, bsel),
                                        bcast(bx.z, bsel), bcast(bx.w, bsel));
                float pa = bcast(ar, bsel);
                alive &= ~__ballot(iou_gt_half(bx, ar, pb, pa));
            }
            if (lane == 0) s_kept = kept;
        }
        __syncthreads();                   // B2
        keptc = s_kept;
        if (s_done) break;
        if (__popcll(vball) < 64) break;   // sorted: nothing valid beyond
    }
    __syncthreads();
    const int kept_final = s_kept;

    // emit 200 keys; low32 packs ((0x3FFF - (c*200+slot)) << 11) | orig_idx
    // -> cross-class order (score desc, flat asc) matches reference top_k
    const int base_o = bc * OUT_K;
    if (tid < OUT_K) {
        u64 ok = 0ULL;
        if (tid < kept_final) {
            u64 kk = key[kept_slot[tid]];
            u32 flat = (u32)(c * OUT_K + tid);
            u32 orig = 0xFFFFFFFFu - (u32)(kk & 0xFFFFFFFFu);   // < 2048
            ok = (kk & 0xFFFFFFFF00000000ULL) |
                 ((u64)(0x3FFFu - flat) << 11) | (u64)orig;
        }
        cand_key[base_o + tid] = ok;
    }
}

// ---- Kernel B1: 80 blocks; tournament-merge 8 desc runs of 200 -> top-256 ----
__global__ __launch_bounds__(256) void topk_stage1(
        const u64* __restrict__ cand_key, u64* __restrict__ ws2) {
    const int b = blockIdx.x / 10, ch = blockIdx.x % 10;
    const int tid = threadIdx.x;
    const int lane = tid & 63;
    const int wv = tid >> 6;
    __shared__ u64 A[2048];
    const u64* src = cand_key + (size_t)b * (NC * OUT_K) + (size_t)ch * 8 * OUT_K;
    for (int i = tid; i < 2048; i += 256) {
        int run = i >> 8, pos = i & 255;
        A[i] = (pos < OUT_K) ? src[run * OUT_K + pos] : 0ULL;
    }
    __syncthreads();
    pair_merge256(A, wv * 512, 256, lane);
    __syncthreads();
    if (wv < 2) pair_merge256(A, wv * 1024, 512, lane);
    __syncthreads();
    if (wv == 0) pair_merge256(A, 0, 1024, lane);
    __syncthreads();
    ws2[(size_t)b * 2560 + ch * 256 + tid] = A[tid];
}

// ---- Kernel B2: 8 blocks; merge 10 runs of 256, decode top-200 ----
__global__ __launch_bounds__(256) void topk_stage2(
        const float* __restrict__ x, const u64* __restrict__ ws2,
        float* __restrict__ out) {
    const int b = blockIdx.x;
    const int tid = threadIdx.x;
    const int lane = tid & 63;
    const int wv = tid >> 6;
    __shared__ u64 A[2560];
    for (int i = tid; i < 2560; i += 256)
        A[i] = ws2[(size_t)b * 2560 + i];
    __syncthreads();
    // tournament over 10 runs of 256:
    // A: (0,256)(512,768)(1024,1280)(1536,1792)(2048,2304)
    pair_merge256(A, wv * 512, 256, lane);
    if (wv == 0) pair_merge256(A, 2048, 256, lane);
    __syncthreads();
    // B: (0,512) and (1024,1536)
    if (wv == 0) pair_merge256(A, 0, 512, lane);
    else if (wv == 1) pair_merge256(A, 1024, 512, lane);
    __syncthreads();
    // C: (0,1024)
    if (wv == 0) pair_merge256(A, 0, 1024, lane);
    __syncthreads();
    // D: (0,2048)
    if (wv == 0) pair_merge256(A, 0, 2048, lane);
    __syncthreads();

    const float* xb = x + (size_t)b * NN * ROW;
    if (tid < OUT_K) {
        u64 kk = A[tid];
        float* o = out + ((size_t)b * OUT_K + tid) * 6;
        if (kk == 0ULL) {
            o[0] = 0.f; o[1] = 0.f; o[2] = 0.f; o[3] = 0.f; o[4] = 0.f; o[5] = 0.f;
        } else {
            u32 lo = (u32)(kk & 0xFFFFFFFFu);
            u32 flat = 0x3FFFu - ((lo >> 11) & 0x3FFFu);  // c*200 + slot
            int cls = flat / OUT_K;
            u32 n = lo & 0x7FFu;
            float scf = __uint_as_float((u32)(kk >> 32));
            float4 bx = *(const float4*)(xb + (size_t)n * ROW);
            o[0] = (float)cls;
            o[1] = scf;
            o[2] = fminf(fmaxf(bx.x, 0.0f), 1.0f);
            o[3] = fminf(fmaxf(bx.y, 0.0f), 1.0f);
            o[4] = fminf(fmaxf(bx.z, 0.0f), 1.0f);
            o[5] = fminf(fmaxf(bx.w, 0.0f), 1.0f);
        }
    }
}

extern "C" void kernel_launch(void* const* d_in, const int* in_sizes, int n_in,
                              void* d_out, int out_size, void* d_ws, size_t ws_size,
                              hipStream_t stream) {
    const float* x = (const float*)d_in[0];
    float* out = (float*)d_out;
    // ws: cand_key 8*80*200*8 = 1,024,000 B ; ws2 8*2560*8 = 163,840 B
    u64* cand_key = (u64*)d_ws;
    u64* ws2 = (u64*)((char*)d_ws + 1024000);
    nms_kernel<<<NB * NC, 256, 0, stream>>>(x, cand_key);
    topk_stage1<<<NB * 10, 256, 0, stream>>>(cand_key, ws2);
    topk_stage2<<<NB, 256, 0, stream>>>(x, ws2, out);
}